// Round 4
// baseline (86.457 us; speedup 1.0000x reference)
//
#include <hip/hip_runtime.h>

// Fused GNN actor: proj -> GraphConv1+tanh -> GraphConv2+tanh -> heads(loc, softplus scale)
// Block = 256 threads (4 waves) = 16 graphs. H in LDS bf16, swizzle (row&7)<<4.
// Per M-tile: acc = AGG@Wrel + H@Wroot + brel, four MFMAs chained into one f32x4.
// Conv/heads weights pre-packed to d_ws as bf16 B-fragments, read DIRECTLY from global (L2).
// LDS = 26816 B (H + S + x stage) -> 6 blocks/CU with __launch_bounds__(256,6).

typedef __attribute__((ext_vector_type(8))) short bf16x8;
typedef __attribute__((ext_vector_type(4))) float f32x4;

#define SOFTPLUS_BIAS 0.5413248546129181f

// ---- LDS byte offsets ----
#define LDS_H   0        // 144 rows x 128B bf16, swizzled by ((row&7)<<4)
#define LDS_S   18432    // 16 rows x 128B bf16, swizzled
#define LDS_X   20480    // 1584 fp32 staged x chunk
#define LDS_SZ  26816

__device__ __forceinline__ unsigned int cvtpk(float lo, float hi) {
  unsigned int r;
  asm("v_cvt_pk_bf16_f32 %0, %1, %2" : "=v"(r) : "v"(lo), "v"(hi));
  return r;
}
__device__ __forceinline__ float asf(unsigned int u) {
  union { unsigned int i; float f; } v; v.i = u; return v.f;
}
__device__ __forceinline__ unsigned short f2bf(float f) {  // RNE, pack kernel only
  union { float f; unsigned int i; } v; v.f = f;
  unsigned int lsb = (v.i >> 16) & 1u;
  return (unsigned short)((v.i + 0x7fffu + lsb) >> 16);
}
__device__ __forceinline__ float fast_tanh(float x) {
  float e = __expf(2.0f * x);                       // inf-safe: e=inf -> rcp=0 -> 1
  return 1.0f - 2.0f * __builtin_amdgcn_rcpf(e + 1.0f);
}

// ---- pack kernel: weights -> d_ws as bf16 B-fragments (16x16x32 layout) ----
// elems: [0,4096) Wrel1 | [4096,8192) Wroot1 | [8192,12288) Wrel2 |
//        [12288,16384) Wroot2 | [16384,17408) heads
__global__ void pack_weights(const float* __restrict__ Wrel1, const float* __restrict__ Wroot1,
                             const float* __restrict__ Wrel2, const float* __restrict__ Wroot2,
                             const float* __restrict__ Wheads, unsigned short* __restrict__ ws) {
  int id = blockIdx.x * 256 + threadIdx.x;
  if (id < 16384) {
    const float* W = (id < 4096) ? Wrel1 : (id < 8192) ? Wroot1 : (id < 12288) ? Wrel2 : Wroot2;
    int m = id & 4095;
    int e = m & 7, lane = (m >> 3) & 63, nt = (m >> 9) & 3, ks = m >> 11;
    int k = ((lane >> 4) << 3) + e + (ks << 5);
    int col = (nt << 4) + (lane & 15);
    ws[id] = f2bf(W[k * 64 + col]);
  } else if (id < 17408) {
    int m = id - 16384;
    int e = m & 7, lane = (m >> 3) & 63, ks = m >> 9;
    int k = ((lane >> 4) << 3) + e + (ks << 5);
    int c = lane & 15, j = c >> 1, o = c & 1;
    ws[id] = f2bf(Wheads[(j * 64 + k) * 2 + o]);
  }
}

__launch_bounds__(256, 6)
__global__ void actor_main(const float* __restrict__ x,
                           const float* __restrict__ Wj_g, const float* __restrict__ bj_g,
                           const float* __restrict__ Wt_g, const float* __restrict__ bt_g,
                           const float* __restrict__ brel1_g, const float* __restrict__ brel2_g,
                           const float* __restrict__ bh_g,
                           const unsigned short* __restrict__ wsw,
                           float* __restrict__ out) {
  __shared__ __align__(16) unsigned char smem[LDS_SZ];
  const int t = threadIdx.x;
  const int lane = t & 63;
  const int w = t >> 6;                 // wave id = N-tile (16 cols) for conv GEMMs
  const int gbase = blockIdx.x << 4;    // 16 graphs per block
  const int l15 = lane & 15;
  const int q = lane >> 4;
  const int ks16 = q << 4;              // A/B frag k-slice byte offset {0,16,32,48}
  const int relc = l15 + (w << 4);      // this wave's output column

  const bf16x8* wsv = reinterpret_cast<const bf16x8*>(wsw);   // 16B frag units

  // ---- address precompute (layer-invariant) ----
  unsigned int aggA[9];                 // AGG A-frag gather addr per M-tile
#pragma unroll
  for (int m = 0; m < 9; m++) {
    int r = (m << 4) + l15;
    int g = (57 * r) >> 9;              // exact r/9 for r<144
    int node = r - 9 * g;
    int row = (node == 0) ? g : 9 * g;  // torso row uses S(g); joint rows use T(g)=H[9g]
    unsigned int base = (node == 0) ? (unsigned)LDS_S : 0u;
    aggA[m] = base + row * 128 + (ks16 ^ ((row & 7) << 4));
  }
  const unsigned int h0b = l15 * 128 + (unsigned)(ks16 ^ ((l15 & 7) << 4));  // H A-frag base (+m*2048)
  unsigned int wb[4];                   // tanh-write bases (+m*2048)
#pragma unroll
  for (int i = 0; i < 4; i++) {
    int rr = (q << 2) + i;
    wb[i] = rr * 128 + (unsigned)((2 * relc) ^ ((rr & 7) << 4));
  }

  // ---- stage x into LDS_X ----
  {
    const float4* xg = reinterpret_cast<const float4*>(x + (size_t)gbase * 99);
    float4* xl4 = reinterpret_cast<float4*>(smem + LDS_X);
    xl4[t] = xg[t];                                  // 396 float4 per block
    if (t + 256 < 396) xl4[t + 256] = xg[t + 256];
  }
  // per-thread weight regs (thread's out-dim = lane for proj)
  float Wtr[11];
#pragma unroll
  for (int k = 0; k < 11; k++) Wtr[k] = Wt_g[k * 64 + lane];
  const float btr = bt_g[lane];
  const float Wj0 = Wj_g[lane], Wj1 = Wj_g[64 + lane], bjr = bj_g[lane];
  const float brelA = brel1_g[relc], brelB = brel2_g[relc];
  __syncthreads();

  // ---- input projection (VALU; x broadcast from LDS) ----
  const float* xl = reinterpret_cast<const float*>(smem + LDS_X);
#pragma unroll
  for (int it = 0; it < 4; it++) {                   // torso rows
    int g = w + (it << 2);
    float acc1 = btr;
#pragma unroll
    for (int k = 0; k < 11; k++) acc1 += xl[g * 99 + k] * Wtr[k];
    int row = 9 * g;
    *reinterpret_cast<unsigned short*>(smem + row * 128 + ((2 * lane) ^ ((row & 7) << 4))) =
        (unsigned short)cvtpk(acc1, acc1);
  }
#pragma unroll
  for (int it = 0; it < 32; it++) {                  // joint rows
    int jr = w + (it << 2);
    int g = jr >> 3, j = jr & 7;
    int xb = g * 99 + 11 + 11 * j;
    float acc1 = bjr + xl[xb] * Wj0 + xl[xb + 1] * Wj1;
    int row = 9 * g + 1 + j;
    *reinterpret_cast<unsigned short*>(smem + row * 128 + ((2 * lane) ^ ((row & 7) << 4))) =
        (unsigned short)cvtpk(acc1, acc1);
  }
  __syncthreads();

  f32x4 acc[9];
#pragma unroll
  for (int layer = 0; layer < 2; layer++) {
    // ---- B-frags for this layer: direct global loads (L2), issued before S-pass ----
    const int lbase = layer ? 1024 : 0;              // frag units (8192 elems / 8)
    bf16x8 bRel0  = wsv[lbase + (0 + w) * 64 + lane];
    bf16x8 bRel1  = wsv[lbase + (4 + w) * 64 + lane];
    bf16x8 bRoot0 = wsv[lbase + 512 + (0 + w) * 64 + lane];
    bf16x8 bRoot1 = wsv[lbase + 512 + (4 + w) * 64 + lane];
    const float brel = layer ? brelB : brelA;

    // ---- S pass: S[g][d] = sum_j H[9g+1+j][d]; thread = (g = t>>4, 4 dims) ----
    {
      int gS = t >> 4, dq = t & 15;
      int rb = dq << 3;
      float s0 = 0.f, s1 = 0.f, s2 = 0.f, s3 = 0.f;
#pragma unroll
      for (int j = 0; j < 8; j++) {
        int row = 9 * gS + 1 + j;
        uint2 p = *reinterpret_cast<const uint2*>(smem + row * 128 + (rb ^ ((row & 7) << 4)));
        s0 += asf(p.x << 16); s1 += asf(p.x & 0xffff0000u);
        s2 += asf(p.y << 16); s3 += asf(p.y & 0xffff0000u);
      }
      uint2 o; o.x = cvtpk(s0, s1); o.y = cvtpk(s2, s3);
      *reinterpret_cast<uint2*>(smem + LDS_S + gS * 128 + (rb ^ ((gS & 7) << 4))) = o;
    }
    __syncthreads();   // S ready

    // ---- fused REL+ROOT GEMM: 9 M-tiles x 4 chained MFMA ----
#pragma unroll
    for (int m = 0; m < 9; m++) {
      bf16x8 ag0 = *reinterpret_cast<const bf16x8*>(smem + aggA[m]);
      bf16x8 ag1 = *reinterpret_cast<const bf16x8*>(smem + (aggA[m] ^ 64u));
      bf16x8 a0  = *reinterpret_cast<const bf16x8*>(smem + h0b + m * 2048);
      bf16x8 a1  = *reinterpret_cast<const bf16x8*>(smem + (h0b ^ 64u) + m * 2048);
      f32x4 c = {brel, brel, brel, brel};
      c = __builtin_amdgcn_mfma_f32_16x16x32_bf16(ag0, bRel0, c, 0, 0, 0);
      c = __builtin_amdgcn_mfma_f32_16x16x32_bf16(ag1, bRel1, c, 0, 0, 0);
      c = __builtin_amdgcn_mfma_f32_16x16x32_bf16(a0, bRoot0, c, 0, 0, 0);
      acc[m] = __builtin_amdgcn_mfma_f32_16x16x32_bf16(a1, bRoot1, c, 0, 0, 0);
    }
    __syncthreads();   // all H/S reads done -> safe to overwrite H

    // ---- tanh + packed-cvt + write H in place ----
#pragma unroll
    for (int m = 0; m < 9; m++) {
      const int off = m * 2048;
      unsigned p0 = cvtpk(fast_tanh(acc[m][0]), fast_tanh(acc[m][1]));
      unsigned p1 = cvtpk(fast_tanh(acc[m][2]), fast_tanh(acc[m][3]));
      *reinterpret_cast<unsigned short*>(smem + wb[0] + off) = (unsigned short)p0;
      *reinterpret_cast<unsigned short*>(smem + wb[1] + off) = (unsigned short)(p0 >> 16);
      *reinterpret_cast<unsigned short*>(smem + wb[2] + off) = (unsigned short)p1;
      *reinterpret_cast<unsigned short*>(smem + wb[3] + off) = (unsigned short)(p1 >> 16);
    }
    __syncthreads();
  }

  // ---- heads: packed B [64,16], cols=(j,o); predicated scatter + softplus ----
  {
    bf16x8 hb0 = wsv[2048 + lane];                   // heads frags (elem 16384 -> frag 2048)
    bf16x8 hb1 = wsv[2048 + 64 + lane];
    int c = l15;
#pragma unroll
    for (int u = 0; u < 2; u++) {
      int tt = (w << 1) + u;
      int jr = (tt << 4) + l15;
      int arow = 9 * (jr >> 3) + 1 + (jr & 7);
      unsigned ha = arow * 128 + (unsigned)(ks16 ^ ((arow & 7) << 4));
      bf16x8 a0 = *reinterpret_cast<const bf16x8*>(smem + ha);
      bf16x8 a1 = *reinterpret_cast<const bf16x8*>(smem + (ha ^ 64u));
      f32x4 z = {0.f, 0.f, 0.f, 0.f};
      z = __builtin_amdgcn_mfma_f32_16x16x32_bf16(a0, hb0, z, 0, 0, 0);
      z = __builtin_amdgcn_mfma_f32_16x16x32_bf16(a1, hb1, z, 0, 0, 0);
#pragma unroll
      for (int i = 0; i < 4; i++) {
        int r = (tt << 4) + (q << 2) + i;            // joint index of this D row
        int gg = r >> 3, j2 = r & 7;
        if (c == 2 * j2) {
          out[(size_t)(gbase + gg) * 8 + j2] = z[i] + bh_g[2 * j2];
        } else if (c == 2 * j2 + 1) {
          float zz = z[i] + bh_g[2 * j2 + 1] + SOFTPLUS_BIAS;
          float sp = (zz > 20.0f) ? zz : __logf(1.0f + __expf(zz));
          out[524288 + (size_t)(gbase + gg) * 8 + j2] = sp;
        }
      }
    }
  }
}

extern "C" void kernel_launch(void* const* d_in, const int* in_sizes, int n_in,
                              void* d_out, int out_size, void* d_ws, size_t ws_size,
                              hipStream_t stream) {
  const float* x      = (const float*)d_in[0];
  // d_in[1] = edge_index (star structure hardcoded)
  const float* Wj     = (const float*)d_in[2];
  const float* bj     = (const float*)d_in[3];
  const float* Wt     = (const float*)d_in[4];
  const float* bt     = (const float*)d_in[5];
  const float* Wrel1  = (const float*)d_in[6];
  const float* brel1  = (const float*)d_in[7];
  const float* Wroot1 = (const float*)d_in[8];
  const float* Wrel2  = (const float*)d_in[9];
  const float* brel2  = (const float*)d_in[10];
  const float* Wroot2 = (const float*)d_in[11];
  const float* Wheads = (const float*)d_in[12];
  const float* bh     = (const float*)d_in[13];
  unsigned short* ws16 = (unsigned short*)d_ws;
  float* out = (float*)d_out;

  hipLaunchKernelGGL(pack_weights, dim3(68), dim3(256), 0, stream,
                     Wrel1, Wroot1, Wrel2, Wroot2, Wheads, ws16);
  hipLaunchKernelGGL(actor_main, dim3(4096), dim3(256), 0, stream,
                     x, Wj, bj, Wt, bt, brel1, brel2, bh, ws16, out);
}

// Round 5
// 63.603 us; speedup vs baseline: 1.3593x; 1.3593x over previous
//
#include <hip/hip_runtime.h>

// Fused GNN actor: proj -> GraphConv1+tanh -> GraphConv2+tanh -> heads(loc, softplus scale)
// Block = 256 threads (4 waves) = 16 graphs. H in LDS bf16, swizzle (row&7)<<4.
// Per M-tile: acc = AGG@Wrel + H@Wroot + brel, four MFMAs chained into one f32x4.
// Weights pre-packed as bf16 B-fragments, read DIRECTLY from global (L2-resident).
// S1 folded into the VALU proj via linearity: S1[g] = 8*bj + (sum_j x0)*Wj0 + (sum_j x1)*Wj1.
// LDS = 26816 B (H + S + x stage); __launch_bounds__(256,5).

typedef __attribute__((ext_vector_type(8))) short bf16x8;
typedef __attribute__((ext_vector_type(4))) float f32x4;

#define SOFTPLUS_BIAS 0.5413248546129181f

// ---- LDS byte offsets ----
#define LDS_H   0        // 144 rows x 128B bf16, swizzled by ((row&7)<<4)
#define LDS_S   18432    // 16 rows x 128B bf16, swizzled
#define LDS_X   20480    // 1584 fp32 staged x chunk
#define LDS_SZ  26816

__device__ __forceinline__ unsigned int cvtpk(float lo, float hi) {
  unsigned int r;
  asm("v_cvt_pk_bf16_f32 %0, %1, %2" : "=v"(r) : "v"(lo), "v"(hi));
  return r;
}
__device__ __forceinline__ float asf(unsigned int u) {
  union { unsigned int i; float f; } v; v.i = u; return v.f;
}
__device__ __forceinline__ unsigned short f2bf(float f) {  // RNE, pack kernel only
  union { float f; unsigned int i; } v; v.f = f;
  unsigned int lsb = (v.i >> 16) & 1u;
  return (unsigned short)((v.i + 0x7fffu + lsb) >> 16);
}
__device__ __forceinline__ float fast_tanh(float x) {
  float e = __expf(2.0f * x);                       // inf-safe: e=inf -> rcp=0 -> 1
  return 1.0f - 2.0f * __builtin_amdgcn_rcpf(e + 1.0f);
}

// ---- pack kernel: weights -> d_ws as bf16 B-fragments (16x16x32 layout) ----
// elems: [0,4096) Wrel1 | [4096,8192) Wroot1 | [8192,12288) Wrel2 |
//        [12288,16384) Wroot2 | [16384,17408) heads
__global__ void pack_weights(const float* __restrict__ Wrel1, const float* __restrict__ Wroot1,
                             const float* __restrict__ Wrel2, const float* __restrict__ Wroot2,
                             const float* __restrict__ Wheads, unsigned short* __restrict__ ws) {
  int id = blockIdx.x * 256 + threadIdx.x;
  if (id < 16384) {
    const float* W = (id < 4096) ? Wrel1 : (id < 8192) ? Wroot1 : (id < 12288) ? Wrel2 : Wroot2;
    int m = id & 4095;
    int e = m & 7, lane = (m >> 3) & 63, nt = (m >> 9) & 3, ks = m >> 11;
    int k = ((lane >> 4) << 3) + e + (ks << 5);
    int col = (nt << 4) + (lane & 15);
    ws[id] = f2bf(W[k * 64 + col]);
  } else if (id < 17408) {
    int m = id - 16384;
    int e = m & 7, lane = (m >> 3) & 63, ks = m >> 9;
    int k = ((lane >> 4) << 3) + e + (ks << 5);
    int c = lane & 15, j = c >> 1, o = c & 1;
    ws[id] = f2bf(Wheads[(j * 64 + k) * 2 + o]);
  }
}

__launch_bounds__(256, 5)
__global__ void actor_main(const float* __restrict__ x,
                           const float* __restrict__ Wj_g, const float* __restrict__ bj_g,
                           const float* __restrict__ Wt_g, const float* __restrict__ bt_g,
                           const float* __restrict__ brel1_g, const float* __restrict__ brel2_g,
                           const float* __restrict__ bh_g,
                           const unsigned short* __restrict__ wsw,
                           float* __restrict__ out) {
  __shared__ __align__(16) unsigned char smem[LDS_SZ];
  const int t = threadIdx.x;
  const int lane = t & 63;
  const int w = t >> 6;                 // wave id = N-tile (16 cols) for conv GEMMs
  const int gbase = blockIdx.x << 4;    // 16 graphs per block
  const int l15 = lane & 15;
  const int q = lane >> 4;
  const int ks16 = q << 4;              // A/B frag k-slice byte offset {0,16,32,48}
  const int relc = l15 + (w << 4);      // this wave's output column

  const bf16x8* wsv = reinterpret_cast<const bf16x8*>(wsw);   // 16B frag units

  // ---- stage x into LDS_X ----
  {
    const float4* xg = reinterpret_cast<const float4*>(x + (size_t)gbase * 99);
    float4* xl4 = reinterpret_cast<float4*>(smem + LDS_X);
    xl4[t] = xg[t];                                  // 396 float4 per block
    if (t + 256 < 396) xl4[t + 256] = xg[t + 256];
  }

  // ---- layer-0 B-frags: direct global loads (L2), issued early to hide under proj ----
  bf16x8 bRel0  = wsv[(0 + w) * 64 + lane];
  bf16x8 bRel1  = wsv[(4 + w) * 64 + lane];
  bf16x8 bRoot0 = wsv[512 + (0 + w) * 64 + lane];
  bf16x8 bRoot1 = wsv[512 + (4 + w) * 64 + lane];

  // per-thread weight regs (thread's out-dim = lane for proj)
  float Wtr[11];
#pragma unroll
  for (int k = 0; k < 11; k++) Wtr[k] = Wt_g[k * 64 + lane];
  const float btr = bt_g[lane];
  const float Wj0 = Wj_g[lane], Wj1 = Wj_g[64 + lane], bjr = bj_g[lane];
  const float brelA = brel1_g[relc], brelB = brel2_g[relc];

  // ---- address precompute (layer-invariant) ----
  unsigned int aggA[9];                 // AGG A-frag gather addr per M-tile
#pragma unroll
  for (int m = 0; m < 9; m++) {
    int r = (m << 4) + l15;
    int g = (57 * r) >> 9;              // exact r/9 for r<144
    int node = r - 9 * g;
    int row = (node == 0) ? g : 9 * g;  // torso row uses S(g); joint rows use T(g)=H[9g]
    unsigned int base = (node == 0) ? (unsigned)LDS_S : 0u;
    aggA[m] = base + row * 128 + (ks16 ^ ((row & 7) << 4));
  }
  const unsigned int h0b = l15 * 128 + (unsigned)(ks16 ^ ((l15 & 7) << 4));  // H A-frag base (+m*2048)
  unsigned int wb[4];                   // tanh-write bases (+m*2048)
#pragma unroll
  for (int i = 0; i < 4; i++) {
    int rr = (q << 2) + i;
    wb[i] = rr * 128 + (unsigned)((2 * relc) ^ ((rr & 7) << 4));
  }
  __syncthreads();

  // ---- input projection (VALU; x broadcast from LDS); S1 folded in by linearity ----
  const float* xl = reinterpret_cast<const float*>(smem + LDS_X);
#pragma unroll
  for (int it = 0; it < 4; it++) {                   // torso rows
    int g = w + (it << 2);
    float acc1 = btr;
#pragma unroll
    for (int k = 0; k < 11; k++) acc1 += xl[g * 99 + k] * Wtr[k];
    int row = 9 * g;
    *reinterpret_cast<unsigned short*>(smem + row * 128 + ((2 * lane) ^ ((row & 7) << 4))) =
        (unsigned short)cvtpk(acc1, acc1);
  }
#pragma unroll
  for (int it = 0; it < 4; it++) {                   // joint rows, one graph per iter
    int g = w + (it << 2);
    float sx0 = 0.f, sx1 = 0.f;
#pragma unroll
    for (int j = 0; j < 8; j++) {
      float x0 = xl[g * 99 + 11 + 11 * j];
      float x1 = xl[g * 99 + 12 + 11 * j];
      sx0 += x0; sx1 += x1;
      float acc1 = bjr + x0 * Wj0 + x1 * Wj1;
      int row = 9 * g + 1 + j;
      *reinterpret_cast<unsigned short*>(smem + row * 128 + ((2 * lane) ^ ((row & 7) << 4))) =
          (unsigned short)cvtpk(acc1, acc1);
    }
    // S1[g][lane] = sum_j h_joint = 8*bj + (sum x0)*Wj0 + (sum x1)*Wj1
    float s = 8.0f * bjr + sx0 * Wj0 + sx1 * Wj1;
    *reinterpret_cast<unsigned short*>(smem + LDS_S + g * 128 + ((2 * lane) ^ ((g & 7) << 4))) =
        (unsigned short)cvtpk(s, s);
  }
  __syncthreads();

  f32x4 acc[9];
#pragma unroll
  for (int layer = 0; layer < 2; layer++) {
    const float brel = layer ? brelB : brelA;

    if (layer == 1) {
      // layer-1 B-frags (issued before S2-pass so L2 latency hides under it)
      bRel0  = wsv[1024 + (0 + w) * 64 + lane];
      bRel1  = wsv[1024 + (4 + w) * 64 + lane];
      bRoot0 = wsv[1024 + 512 + (0 + w) * 64 + lane];
      bRoot1 = wsv[1024 + 512 + (4 + w) * 64 + lane];
      // ---- S2 pass: S[g][d] = sum_j tanh-H[9g+1+j][d]; thread = (g = t>>4, 4 dims) ----
      int gS = t >> 4, dq = t & 15;
      int rb = dq << 3;
      float s0 = 0.f, s1 = 0.f, s2 = 0.f, s3 = 0.f;
#pragma unroll
      for (int j = 0; j < 8; j++) {
        int row = 9 * gS + 1 + j;
        uint2 p = *reinterpret_cast<const uint2*>(smem + row * 128 + (rb ^ ((row & 7) << 4)));
        s0 += asf(p.x << 16); s1 += asf(p.x & 0xffff0000u);
        s2 += asf(p.y << 16); s3 += asf(p.y & 0xffff0000u);
      }
      uint2 o; o.x = cvtpk(s0, s1); o.y = cvtpk(s2, s3);
      *reinterpret_cast<uint2*>(smem + LDS_S + gS * 128 + (rb ^ ((gS & 7) << 4))) = o;
      __syncthreads();   // S2 ready
    }

    // ---- fused REL+ROOT GEMM: 9 M-tiles x 4 chained MFMA ----
#pragma unroll
    for (int m = 0; m < 9; m++) {
      bf16x8 ag0 = *reinterpret_cast<const bf16x8*>(smem + aggA[m]);
      bf16x8 ag1 = *reinterpret_cast<const bf16x8*>(smem + (aggA[m] ^ 64u));
      bf16x8 a0  = *reinterpret_cast<const bf16x8*>(smem + h0b + m * 2048);
      bf16x8 a1  = *reinterpret_cast<const bf16x8*>(smem + (h0b ^ 64u) + m * 2048);
      f32x4 c = {brel, brel, brel, brel};
      c = __builtin_amdgcn_mfma_f32_16x16x32_bf16(ag0, bRel0, c, 0, 0, 0);
      c = __builtin_amdgcn_mfma_f32_16x16x32_bf16(ag1, bRel1, c, 0, 0, 0);
      c = __builtin_amdgcn_mfma_f32_16x16x32_bf16(a0, bRoot0, c, 0, 0, 0);
      acc[m] = __builtin_amdgcn_mfma_f32_16x16x32_bf16(a1, bRoot1, c, 0, 0, 0);
    }
    __syncthreads();   // all H/S reads done -> safe to overwrite H

    // ---- tanh + packed-cvt + write H in place ----
#pragma unroll
    for (int m = 0; m < 9; m++) {
      const int off = m * 2048;
      unsigned p0 = cvtpk(fast_tanh(acc[m][0]), fast_tanh(acc[m][1]));
      unsigned p1 = cvtpk(fast_tanh(acc[m][2]), fast_tanh(acc[m][3]));
      *reinterpret_cast<unsigned short*>(smem + wb[0] + off) = (unsigned short)p0;
      *reinterpret_cast<unsigned short*>(smem + wb[1] + off) = (unsigned short)(p0 >> 16);
      *reinterpret_cast<unsigned short*>(smem + wb[2] + off) = (unsigned short)p1;
      *reinterpret_cast<unsigned short*>(smem + wb[3] + off) = (unsigned short)(p1 >> 16);
    }
    __syncthreads();
  }

  // ---- heads: packed B [64,16], cols=(j,o); predicated scatter + softplus ----
  {
    bf16x8 hb0 = wsv[2048 + lane];                   // heads frags (elem 16384 -> frag 2048)
    bf16x8 hb1 = wsv[2048 + 64 + lane];
    int c = l15;
#pragma unroll
    for (int u = 0; u < 2; u++) {
      int tt = (w << 1) + u;
      int jr = (tt << 4) + l15;
      int arow = 9 * (jr >> 3) + 1 + (jr & 7);
      unsigned ha = arow * 128 + (unsigned)(ks16 ^ ((arow & 7) << 4));
      bf16x8 a0 = *reinterpret_cast<const bf16x8*>(smem + ha);
      bf16x8 a1 = *reinterpret_cast<const bf16x8*>(smem + (ha ^ 64u));
      f32x4 z = {0.f, 0.f, 0.f, 0.f};
      z = __builtin_amdgcn_mfma_f32_16x16x32_bf16(a0, hb0, z, 0, 0, 0);
      z = __builtin_amdgcn_mfma_f32_16x16x32_bf16(a1, hb1, z, 0, 0, 0);
#pragma unroll
      for (int i = 0; i < 4; i++) {
        int r = (tt << 4) + (q << 2) + i;            // joint index of this D row
        int gg = r >> 3, j2 = r & 7;
        if (c == 2 * j2) {
          out[(size_t)(gbase + gg) * 8 + j2] = z[i] + bh_g[2 * j2];
        } else if (c == 2 * j2 + 1) {
          float zz = z[i] + bh_g[2 * j2 + 1] + SOFTPLUS_BIAS;
          float sp = (zz > 20.0f) ? zz : __logf(1.0f + __expf(zz));
          out[524288 + (size_t)(gbase + gg) * 8 + j2] = sp;
        }
      }
    }
  }
}

extern "C" void kernel_launch(void* const* d_in, const int* in_sizes, int n_in,
                              void* d_out, int out_size, void* d_ws, size_t ws_size,
                              hipStream_t stream) {
  const float* x      = (const float*)d_in[0];
  // d_in[1] = edge_index (star structure hardcoded)
  const float* Wj     = (const float*)d_in[2];
  const float* bj     = (const float*)d_in[3];
  const float* Wt     = (const float*)d_in[4];
  const float* bt     = (const float*)d_in[5];
  const float* Wrel1  = (const float*)d_in[6];
  const float* brel1  = (const float*)d_in[7];
  const float* Wroot1 = (const float*)d_in[8];
  const float* Wrel2  = (const float*)d_in[9];
  const float* brel2  = (const float*)d_in[10];
  const float* Wroot2 = (const float*)d_in[11];
  const float* Wheads = (const float*)d_in[12];
  const float* bh     = (const float*)d_in[13];
  unsigned short* ws16 = (unsigned short*)d_ws;
  float* out = (float*)d_out;

  hipLaunchKernelGGL(pack_weights, dim3(68), dim3(256), 0, stream,
                     Wrel1, Wroot1, Wrel2, Wroot2, Wheads, ws16);
  hipLaunchKernelGGL(actor_main, dim3(4096), dim3(256), 0, stream,
                     x, Wj, bj, Wt, bt, brel1, brel2, bh, ws16, out);
}

// Round 6
// 63.053 us; speedup vs baseline: 1.3712x; 1.0087x over previous
//
#include <hip/hip_runtime.h>

// Fused GNN actor: proj -> GraphConv1+tanh -> GraphConv2+tanh -> heads(loc, softplus scale)
// Block = 256 threads (4 waves) = 16 graphs. H in LDS bf16, swizzle (row&7)<<4.
// Per M-tile: acc = AGG@Wrel + H@Wroot + brel, four MFMAs chained into one f32x4.
// Weights pre-packed as bf16 B-fragments, read DIRECTLY from global (L2-resident).
// S1 folded into the VALU proj via linearity: S1[g] = 8*bj + (sum_j x0)*Wj0 + (sum_j x1)*Wj1.
// x read via wave-uniform SGPR pointers (s_load path) -> no x staging, no LDS broadcasts.
// LDS = 20480 B (H + S only); __launch_bounds__(256,5).

typedef __attribute__((ext_vector_type(8))) short bf16x8;
typedef __attribute__((ext_vector_type(4))) float f32x4;

#define SOFTPLUS_BIAS 0.5413248546129181f

// ---- LDS byte offsets ----
#define LDS_H   0        // 144 rows x 128B bf16, swizzled by ((row&7)<<4)
#define LDS_S   18432    // 16 rows x 128B bf16, swizzled
#define LDS_SZ  20480

__device__ __forceinline__ unsigned int cvtpk(float lo, float hi) {
  unsigned int r;
  asm("v_cvt_pk_bf16_f32 %0, %1, %2" : "=v"(r) : "v"(lo), "v"(hi));
  return r;
}
__device__ __forceinline__ float asf(unsigned int u) {
  union { unsigned int i; float f; } v; v.i = u; return v.f;
}
__device__ __forceinline__ unsigned short f2bf(float f) {  // RNE, pack kernel only
  union { float f; unsigned int i; } v; v.f = f;
  unsigned int lsb = (v.i >> 16) & 1u;
  return (unsigned short)((v.i + 0x7fffu + lsb) >> 16);
}
__device__ __forceinline__ float fast_tanh(float x) {
  float e = __expf(2.0f * x);                       // inf-safe: e=inf -> rcp=0 -> 1
  return 1.0f - 2.0f * __builtin_amdgcn_rcpf(e + 1.0f);
}

// ---- pack kernel: weights -> d_ws as bf16 B-fragments (16x16x32 layout) ----
// elems: [0,4096) Wrel1 | [4096,8192) Wroot1 | [8192,12288) Wrel2 |
//        [12288,16384) Wroot2 | [16384,17408) heads
__global__ void pack_weights(const float* __restrict__ Wrel1, const float* __restrict__ Wroot1,
                             const float* __restrict__ Wrel2, const float* __restrict__ Wroot2,
                             const float* __restrict__ Wheads, unsigned short* __restrict__ ws) {
  int id = blockIdx.x * 256 + threadIdx.x;
  if (id < 16384) {
    const float* W = (id < 4096) ? Wrel1 : (id < 8192) ? Wroot1 : (id < 12288) ? Wrel2 : Wroot2;
    int m = id & 4095;
    int e = m & 7, lane = (m >> 3) & 63, nt = (m >> 9) & 3, ks = m >> 11;
    int k = ((lane >> 4) << 3) + e + (ks << 5);
    int col = (nt << 4) + (lane & 15);
    ws[id] = f2bf(W[k * 64 + col]);
  } else if (id < 17408) {
    int m = id - 16384;
    int e = m & 7, lane = (m >> 3) & 63, ks = m >> 9;
    int k = ((lane >> 4) << 3) + e + (ks << 5);
    int c = lane & 15, j = c >> 1, o = c & 1;
    ws[id] = f2bf(Wheads[(j * 64 + k) * 2 + o]);
  }
}

__launch_bounds__(256, 5)
__global__ void actor_main(const float* __restrict__ x,
                           const float* __restrict__ Wj_g, const float* __restrict__ bj_g,
                           const float* __restrict__ Wt_g, const float* __restrict__ bt_g,
                           const float* __restrict__ brel1_g, const float* __restrict__ brel2_g,
                           const float* __restrict__ bh_g,
                           const unsigned short* __restrict__ wsw,
                           float* __restrict__ out) {
  __shared__ __align__(16) unsigned char smem[LDS_SZ];
  const int t = threadIdx.x;
  const int lane = t & 63;
  const int w = t >> 6;                 // wave id = N-tile (16 cols) for conv GEMMs
  const int gbase = blockIdx.x << 4;    // 16 graphs per block
  const int l15 = lane & 15;
  const int q = lane >> 4;
  const int ks16 = q << 4;              // A/B frag k-slice byte offset {0,16,32,48}
  const int relc = l15 + (w << 4);      // this wave's output column

  const bf16x8* wsv = reinterpret_cast<const bf16x8*>(wsw);   // 16B frag units

  // ---- layer-0 B-frags: direct global loads (L2), issued early to hide under proj ----
  bf16x8 bRel0  = wsv[(0 + w) * 64 + lane];
  bf16x8 bRel1  = wsv[(4 + w) * 64 + lane];
  bf16x8 bRoot0 = wsv[512 + (0 + w) * 64 + lane];
  bf16x8 bRoot1 = wsv[512 + (4 + w) * 64 + lane];

  // per-thread weight regs (thread's out-dim = lane for proj)
  float Wtr[11];
#pragma unroll
  for (int k = 0; k < 11; k++) Wtr[k] = Wt_g[k * 64 + lane];
  const float btr = bt_g[lane];
  const float Wj0 = Wj_g[lane], Wj1 = Wj_g[64 + lane], bjr = bj_g[lane];
  const float brelA = brel1_g[relc], brelB = brel2_g[relc];

  // ---- address precompute (layer-invariant) ----
  unsigned int aggA[9];                 // AGG A-frag gather addr per M-tile
#pragma unroll
  for (int m = 0; m < 9; m++) {
    int r = (m << 4) + l15;
    int g = (57 * r) >> 9;              // exact r/9 for r<144
    int node = r - 9 * g;
    int row = (node == 0) ? g : 9 * g;  // torso row uses S(g); joint rows use T(g)=H[9g]
    unsigned int base = (node == 0) ? (unsigned)LDS_S : 0u;
    aggA[m] = base + row * 128 + (ks16 ^ ((row & 7) << 4));
  }
  const unsigned int h0b = l15 * 128 + (unsigned)(ks16 ^ ((l15 & 7) << 4));  // H A-frag base (+m*2048)
  unsigned int wb[4];                   // tanh-write bases (+m*2048)
#pragma unroll
  for (int i = 0; i < 4; i++) {
    int rr = (q << 2) + i;
    wb[i] = rr * 128 + (unsigned)((2 * relc) ^ ((rr & 7) << 4));
  }

  // ---- input projection (x via wave-uniform SGPR pointers -> scalar loads) ----
  // Each wave handles graphs {w, w+4, w+8, w+12}; S1 folded in by linearity.
  const int w_u = __builtin_amdgcn_readfirstlane(w);
#pragma unroll
  for (int it = 0; it < 4; it++) {
    const int g = w_u + (it << 2);
    const float* __restrict__ xr = x + (size_t)(gbase + g) * 99;
    // torso row
    float acc1 = btr;
#pragma unroll
    for (int k = 0; k < 11; k++) acc1 += xr[k] * Wtr[k];
    int trow = 9 * g;
    *reinterpret_cast<unsigned short*>(smem + trow * 128 + ((2 * lane) ^ ((trow & 7) << 4))) =
        (unsigned short)cvtpk(acc1, acc1);
    // joint rows + S1 accumulation
    float sx0 = 0.f, sx1 = 0.f;
#pragma unroll
    for (int j = 0; j < 8; j++) {
      float x0 = xr[11 + 11 * j];
      float x1 = xr[12 + 11 * j];
      sx0 += x0; sx1 += x1;
      float accj = bjr + x0 * Wj0 + x1 * Wj1;
      int row = 9 * g + 1 + j;
      *reinterpret_cast<unsigned short*>(smem + row * 128 + ((2 * lane) ^ ((row & 7) << 4))) =
          (unsigned short)cvtpk(accj, accj);
    }
    float s = 8.0f * bjr + sx0 * Wj0 + sx1 * Wj1;
    *reinterpret_cast<unsigned short*>(smem + LDS_S + g * 128 + ((2 * lane) ^ ((g & 7) << 4))) =
        (unsigned short)cvtpk(s, s);
  }
  __syncthreads();

  f32x4 acc[9];
#pragma unroll
  for (int layer = 0; layer < 2; layer++) {
    const float brel = layer ? brelB : brelA;

    if (layer == 1) {
      // layer-1 B-frags (issued before S2-pass so L2 latency hides under it)
      bRel0  = wsv[1024 + (0 + w) * 64 + lane];
      bRel1  = wsv[1024 + (4 + w) * 64 + lane];
      bRoot0 = wsv[1024 + 512 + (0 + w) * 64 + lane];
      bRoot1 = wsv[1024 + 512 + (4 + w) * 64 + lane];
      // ---- S2 pass: S[g][d] = sum_j tanh-H[9g+1+j][d]; thread = (g = t>>4, 4 dims) ----
      int gS = t >> 4, dq = t & 15;
      int rb = dq << 3;
      float s0 = 0.f, s1 = 0.f, s2 = 0.f, s3 = 0.f;
#pragma unroll
      for (int j = 0; j < 8; j++) {
        int row = 9 * gS + 1 + j;
        uint2 p = *reinterpret_cast<const uint2*>(smem + row * 128 + (rb ^ ((row & 7) << 4)));
        s0 += asf(p.x << 16); s1 += asf(p.x & 0xffff0000u);
        s2 += asf(p.y << 16); s3 += asf(p.y & 0xffff0000u);
      }
      uint2 o; o.x = cvtpk(s0, s1); o.y = cvtpk(s2, s3);
      *reinterpret_cast<uint2*>(smem + LDS_S + gS * 128 + (rb ^ ((gS & 7) << 4))) = o;
      __syncthreads();   // S2 ready
    }

    // ---- fused REL+ROOT GEMM: 9 M-tiles x 4 chained MFMA ----
#pragma unroll
    for (int m = 0; m < 9; m++) {
      bf16x8 ag0 = *reinterpret_cast<const bf16x8*>(smem + aggA[m]);
      bf16x8 ag1 = *reinterpret_cast<const bf16x8*>(smem + (aggA[m] ^ 64u));
      bf16x8 a0  = *reinterpret_cast<const bf16x8*>(smem + h0b + m * 2048);
      bf16x8 a1  = *reinterpret_cast<const bf16x8*>(smem + (h0b ^ 64u) + m * 2048);
      f32x4 c = {brel, brel, brel, brel};
      c = __builtin_amdgcn_mfma_f32_16x16x32_bf16(ag0, bRel0, c, 0, 0, 0);
      c = __builtin_amdgcn_mfma_f32_16x16x32_bf16(ag1, bRel1, c, 0, 0, 0);
      c = __builtin_amdgcn_mfma_f32_16x16x32_bf16(a0, bRoot0, c, 0, 0, 0);
      acc[m] = __builtin_amdgcn_mfma_f32_16x16x32_bf16(a1, bRoot1, c, 0, 0, 0);
    }
    __syncthreads();   // all H/S reads done -> safe to overwrite H

    // ---- tanh + packed-cvt + write H in place ----
#pragma unroll
    for (int m = 0; m < 9; m++) {
      const int off = m * 2048;
      unsigned p0 = cvtpk(fast_tanh(acc[m][0]), fast_tanh(acc[m][1]));
      unsigned p1 = cvtpk(fast_tanh(acc[m][2]), fast_tanh(acc[m][3]));
      *reinterpret_cast<unsigned short*>(smem + wb[0] + off) = (unsigned short)p0;
      *reinterpret_cast<unsigned short*>(smem + wb[1] + off) = (unsigned short)(p0 >> 16);
      *reinterpret_cast<unsigned short*>(smem + wb[2] + off) = (unsigned short)p1;
      *reinterpret_cast<unsigned short*>(smem + wb[3] + off) = (unsigned short)(p1 >> 16);
    }
    __syncthreads();
  }

  // ---- heads: packed B [64,16], cols=(j,o); predicated scatter + softplus ----
  {
    bf16x8 hb0 = wsv[2048 + lane];                   // heads frags (elem 16384 -> frag 2048)
    bf16x8 hb1 = wsv[2048 + 64 + lane];
    int c = l15;
#pragma unroll
    for (int u = 0; u < 2; u++) {
      int tt = (w << 1) + u;
      int jr = (tt << 4) + l15;
      int arow = 9 * (jr >> 3) + 1 + (jr & 7);
      unsigned ha = arow * 128 + (unsigned)(ks16 ^ ((arow & 7) << 4));
      bf16x8 a0 = *reinterpret_cast<const bf16x8*>(smem + ha);
      bf16x8 a1 = *reinterpret_cast<const bf16x8*>(smem + (ha ^ 64u));
      f32x4 z = {0.f, 0.f, 0.f, 0.f};
      z = __builtin_amdgcn_mfma_f32_16x16x32_bf16(a0, hb0, z, 0, 0, 0);
      z = __builtin_amdgcn_mfma_f32_16x16x32_bf16(a1, hb1, z, 0, 0, 0);
#pragma unroll
      for (int i = 0; i < 4; i++) {
        int r = (tt << 4) + (q << 2) + i;            // joint index of this D row
        int gg = r >> 3, j2 = r & 7;
        if (c == 2 * j2) {
          out[(size_t)(gbase + gg) * 8 + j2] = z[i] + bh_g[2 * j2];
        } else if (c == 2 * j2 + 1) {
          float zz = z[i] + bh_g[2 * j2 + 1] + SOFTPLUS_BIAS;
          float sp = (zz > 20.0f) ? zz : __logf(1.0f + __expf(zz));
          out[524288 + (size_t)(gbase + gg) * 8 + j2] = sp;
        }
      }
    }
  }
}

extern "C" void kernel_launch(void* const* d_in, const int* in_sizes, int n_in,
                              void* d_out, int out_size, void* d_ws, size_t ws_size,
                              hipStream_t stream) {
  const float* x      = (const float*)d_in[0];
  // d_in[1] = edge_index (star structure hardcoded)
  const float* Wj     = (const float*)d_in[2];
  const float* bj     = (const float*)d_in[3];
  const float* Wt     = (const float*)d_in[4];
  const float* bt     = (const float*)d_in[5];
  const float* Wrel1  = (const float*)d_in[6];
  const float* brel1  = (const float*)d_in[7];
  const float* Wroot1 = (const float*)d_in[8];
  const float* Wrel2  = (const float*)d_in[9];
  const float* brel2  = (const float*)d_in[10];
  const float* Wroot2 = (const float*)d_in[11];
  const float* Wheads = (const float*)d_in[12];
  const float* bh     = (const float*)d_in[13];
  unsigned short* ws16 = (unsigned short*)d_ws;
  float* out = (float*)d_out;

  hipLaunchKernelGGL(pack_weights, dim3(68), dim3(256), 0, stream,
                     Wrel1, Wroot1, Wrel2, Wroot2, Wheads, ws16);
  hipLaunchKernelGGL(actor_main, dim3(4096), dim3(256), 0, stream,
                     x, Wj, bj, Wt, bt, brel1, brel2, bh, ws16, out);
}